// Round 5
// baseline (451.868 us; speedup 1.0000x reference)
//
#include <hip/hip_runtime.h>
#include <math.h>

#define NROWS 4096
#define DDIM  128
#define IMG_ELEMS 50331648LL   // 4096*3*64*64

typedef __attribute__((ext_vector_type(8))) short short8;   // 8 bf16 = 4 VGPRs
typedef __attribute__((ext_vector_type(4))) float floatx4;  // MFMA acc / float4 loads

// ws layout (bytes):
//   [0,64)        : 5 doubles  [0]=mse [1]=kld [2]=Spp [3]=Szz [4]=Spz
//   [64, +16K)    : nP (4096 f32 row norms of prior_z)
//   [.. , +16K)   : nZ
//   then 4 x 1MB  : Phi, Plo, Zhi, Zlo (bf16 as ushort, 4096x128,
//                   FRAGMENT-LINEAR layout: elem (r,c) at
//                   ((r>>4)*4 + (c>>5))*512 + (((c>>3)&3)*16 + (r&15))*8 + (c&7)
//                   so one MFMA fragment = contiguous 1KB in lane order)
#define WS_NP   64
#define WS_NZ   (WS_NP + 16384)
#define WS_PHI  (WS_NZ + 16384)
#define WS_PLO  (WS_PHI + 1048576)
#define WS_ZHI  (WS_PLO + 1048576)
#define WS_ZLO  (WS_ZHI + 1048576)

// Roles: even bids 0..2174 are streamers (1088 = 1024 mse + 64 kld),
// resident from t=0; all other bids are gram (2080 single tiles:
// 528 pp-upper + 528 zz-upper + 1024 pz-full).
#define GRAM_TILES   2080
#define MSE_ITEMS    1024
#define KLD_BLOCKS   64
#define STREAMERS    1088
#define TOTAL_BLOCKS (GRAM_TILES + STREAMERS)   // 3168

__device__ __forceinline__ unsigned short f2bf(float f) {
    unsigned u = __float_as_uint(f);
    unsigned r = (u + 0x7FFFu + ((u >> 16) & 1u)) >> 16;   // RNE
    return (unsigned short)r;
}
__device__ __forceinline__ float bf2f(unsigned short h) {
    return __uint_as_float(((unsigned)h) << 16);
}

__device__ __forceinline__ void block_reduce_atomic(double v, double* dst) {
    #pragma unroll
    for (int o = 32; o > 0; o >>= 1) v += __shfl_down(v, o);
    __shared__ double sm[4];
    int lane = threadIdx.x & 63, wv = threadIdx.x >> 6;
    if (lane == 0) sm[wv] = v;
    __syncthreads();
    if (threadIdx.x == 0) atomicAdd(dst, sm[0] + sm[1] + sm[2] + sm[3]);
}

// 2048 blocks x 256 threads; each wave owns one of 8192 rows (P then Z).
// Splits fp32 -> bf16 hi+lo into FRAGMENT-LINEAR layout, computes exact fp32
// row norms. Block 0 also zeroes the accumulator doubles.
__global__ __launch_bounds__(256) void prep_kernel(const float* __restrict__ P,
                                                   const float* __restrict__ Z,
                                                   char* __restrict__ wsb,
                                                   double* __restrict__ ws) {
    if (blockIdx.x == 0 && threadIdx.x < 8) ws[threadIdx.x] = 0.0;
    const int w = threadIdx.x >> 6;
    const int b = blockIdx.x * 4 + w;    // 0..8191
    const int row = b & 4095;
    const float* src;
    unsigned short *hi, *lo;
    float* nrm;
    if (b < 4096) {
        src = P + (size_t)row * DDIM;
        hi = (unsigned short*)(wsb + WS_PHI);
        lo = (unsigned short*)(wsb + WS_PLO);
        nrm = (float*)(wsb + WS_NP);
    } else {
        src = Z + (size_t)row * DDIM;
        hi = (unsigned short*)(wsb + WS_ZHI);
        lo = (unsigned short*)(wsb + WS_ZLO);
        nrm = (float*)(wsb + WS_NZ);
    }
    const int l = threadIdx.x & 63;      // lane holds cols 2l, 2l+1
    float2 v = ((const float2*)src)[l];
    unsigned short hx = f2bf(v.x), hy = f2bf(v.y);
    unsigned short lx = f2bf(v.x - bf2f(hx)), ly = f2bf(v.y - bf2f(hy));
    // fragment-linear destination (e and e+1 are contiguous: e in {0,2,4,6})
    const int rb = row >> 4, fr = row & 15;
    const int kb = l >> 4, fq = (l >> 2) & 3, e = (l & 3) * 2;
    const int dst = (rb * 4 + kb) * 512 + (fq * 16 + fr) * 8 + e;   // elems
    *(ushort2*)(hi + dst) = make_ushort2(hx, hy);
    *(ushort2*)(lo + dst) = make_ushort2(lx, ly);
    float s = v.x * v.x + v.y * v.y;
    #pragma unroll
    for (int o = 32; o > 0; o >>= 1) s += __shfl_down(s, o);
    if (l == 0) nrm[row] = s;
}

__global__ __launch_bounds__(256) void fused_kernel(char* __restrict__ wsb,
                                                    double* __restrict__ ws,
                                                    const floatx4* __restrict__ rc,
                                                    const floatx4* __restrict__ xx,
                                                    const floatx4* __restrict__ mu,
                                                    const floatx4* __restrict__ lv) {
    const int bid = blockIdx.x;
    const int tid = threadIdx.x, lane = tid & 63, w = tid >> 6;

    const bool is_stream = ((bid & 1) == 0) && ((bid >> 1) < STREAMERS);

    if (is_stream) {
        const int s = bid >> 1;              // 0..1087
        if (s < MSE_ITEMS) {
            // ------------- MSE role: contiguous 192KB chunk per array ------
            // 2-deep pipeline, 16 loads in flight, per-array load batches
            // (8 rc then 8 xx). Arithmetic identical to prior rounds; only
            // load ISSUE ORDER differs (no numerical effect).
            const long long base = (long long)s * 12288 + tid;
            floatx4 s0 = {0.f,0.f,0.f,0.f}, s1 = s0, s2 = s0, s3 = s0;
            #pragma unroll 1
            for (int it = 0; it < 6; ++it) {
                long long i = base + (long long)it * 2048;
                long long j = i + 1024;
                // rc batch (8 loads, 8KB runs per wave)
                floatx4 a0 = rc[i],       a1 = rc[i + 256];
                floatx4 a2 = rc[i + 512], a3 = rc[i + 768];
                floatx4 c0 = rc[j],       c1 = rc[j + 256];
                floatx4 c2 = rc[j + 512], c3 = rc[j + 768];
                // xx batch (8 loads)
                floatx4 b0 = xx[i],       b1 = xx[i + 256];
                floatx4 b2 = xx[i + 512], b3 = xx[i + 768];
                floatx4 d0 = xx[j],       d1 = xx[j + 256];
                floatx4 d2 = xx[j + 512], d3 = xx[j + 768];
                // same accumulator mapping as before: slot k -> s_k
                floatx4 e0 = a0 - b0, e1 = a1 - b1, e2 = a2 - b2, e3 = a3 - b3;
                s0 += e0 * e0; s1 += e1 * e1; s2 += e2 * e2; s3 += e3 * e3;
                floatx4 f0 = c0 - d0, f1 = c1 - d1, f2 = c2 - d2, f3 = c3 - d3;
                s0 += f0 * f0; s1 += f1 * f1; s2 += f2 * f2; s3 += f3 * f3;
            }
            floatx4 st = (s0 + s1) + (s2 + s3);
            double v = ((double)st[0] + (double)st[1]) + ((double)st[2] + (double)st[3]);
            block_reduce_atomic(v, &ws[0]);
        } else {
            // ------------- KLD role: contiguous 32KB chunk per array -------
            const int k = s - MSE_ITEMS;     // 0..63
            const int i = k * 2048 + tid;
            float sm = 0.f;
            #pragma unroll
            for (int q = 0; q < 8; ++q) {
                floatx4 m = mu[i + q * 256], l = lv[i + q * 256];
                sm += (1.f + l[0] - m[0] * m[0] - __expf(l[0]) )
                    + (1.f + l[1] - m[1] * m[1] - __expf(l[1]) )
                    + (1.f + l[2] - m[2] * m[2] - __expf(l[2]) )
                    + (1.f + l[3] - m[3] * m[3] - __expf(l[3]) );
            }
            block_reduce_atomic((double)sm, &ws[1]);
        }
        return;
    }

    // ---------------- GRAM role: no LDS, no barriers -----------------------
    // tile id t in [0,2080): [0,528)=pp upper, [528,1056)=zz upper, rest pz
    const int t = (bid < 2176) ? (bid >> 1) : (bid - 1088);
    int g, by, bx;
    float wgt = 1.f;
    if (t < 1056) {
        g = (t < 528) ? 0 : 1;
        const int u = (t < 528) ? t : t - 528;
        int r = (int)((65.0f - sqrtf(4225.0f - 8.0f * (float)u)) * 0.5f);
        while ((r + 1) * (64 - r) / 2 <= u) ++r;    // cnt(r+1) <= u
        while (r * (65 - r) / 2 > u) --r;           // cnt(r) > u
        const int c = r + (u - r * (65 - r) / 2);
        by = r; bx = c;
        if (r != c) wgt = 2.f;                      // off-diagonal counts twice
    } else {
        g = 2;
        const int u = t - 1056;
        by = u >> 5; bx = u & 31;
    }

    const unsigned short* Phi = (const unsigned short*)(wsb + WS_PHI);
    const unsigned short* Plo = (const unsigned short*)(wsb + WS_PLO);
    const unsigned short* Zhi = (const unsigned short*)(wsb + WS_ZHI);
    const unsigned short* Zlo = (const unsigned short*)(wsb + WS_ZLO);
    const float* nP = (const float*)(wsb + WS_NP);
    const float* nZ = (const float*)(wsb + WS_NZ);
    const unsigned short *Ahi, *Alo, *Bhi, *Blo;
    const float *nI, *nJ;
    if (g == 0)      { Ahi = Phi; Alo = Plo; Bhi = Phi; Blo = Plo; nI = nP; nJ = nP; }
    else if (g == 1) { Ahi = Zhi; Alo = Zlo; Bhi = Zhi; Blo = Zlo; nI = nZ; nJ = nZ; }
    else             { Ahi = Phi; Alo = Plo; Bhi = Zhi; Blo = Zlo; nI = nP; nJ = nZ; }

    const int i0 = by * 128, j0 = bx * 128;
    const int qi = (w >> 1) * 64, qj = (w & 1) * 64;
    const int ra = (i0 + qi) >> 4;       // 16-row fragment block index, A side
    const int rbb = (j0 + qj) >> 4;      // B side

    floatx4 acc[4][4];
    const floatx4 zero4 = {0.f, 0.f, 0.f, 0.f};
    #pragma unroll
    for (int a = 0; a < 4; a++)
        #pragma unroll
        for (int b = 0; b < 4; b++) acc[a][b] = zero4;

    #pragma unroll
    for (int pass = 0; pass < 3; pass++) {
        const short8* As = (const short8*)((pass == 2) ? Alo : Ahi);  // hi,hi,lo
        const short8* Bs = (const short8*)((pass == 1) ? Blo : Bhi);  // hi,lo,hi
        #pragma unroll
        for (int kb = 0; kb < 4; kb++) {
            short8 af[4], bf[4];
            #pragma unroll
            for (int a = 0; a < 4; a++)
                af[a] = As[((ra + a) * 4 + kb) * 64 + lane];   // contiguous 1KB/wave
            #pragma unroll
            for (int b = 0; b < 4; b++)
                bf[b] = Bs[((rbb + b) * 4 + kb) * 64 + lane];
            #pragma unroll
            for (int a = 0; a < 4; a++)
                #pragma unroll
                for (int b = 0; b < 4; b++)
                    acc[a][b] = __builtin_amdgcn_mfma_f32_16x16x32_bf16(
                        af[a], bf[b], acc[a][b], 0, 0, 0);
        }
    }

    // epilogue: k_ij = exp(cc*(2*dot - ni - nj)), cc = 1/(D * 2*D*z_var)
    const float cc = 1.0f / 65536.0f;
    const int fr = lane & 15, fq = lane >> 4;
    float nj_[4];
    #pragma unroll
    for (int b = 0; b < 4; b++) nj_[b] = nJ[j0 + qj + b * 16 + fr];
    float sum = 0.f;
    #pragma unroll
    for (int a = 0; a < 4; a++) {
        #pragma unroll
        for (int r = 0; r < 4; r++) {
            const float ni = nI[i0 + qi + a * 16 + fq * 4 + r];
            #pragma unroll
            for (int b = 0; b < 4; b++)
                sum += expf(cc * (2.f * acc[a][b][r] - ni - nj_[b]));
        }
    }
    sum *= wgt;

    double v = (double)sum;
    #pragma unroll
    for (int o = 32; o > 0; o >>= 1) v += __shfl_down(v, o);
    __shared__ double red[4];
    if (lane == 0) red[w] = v;
    __syncthreads();
    if (tid == 0) atomicAdd(&ws[2 + g], red[0] + red[1] + red[2] + red[3]);
}

__global__ void finalize_kernel(const double* __restrict__ ws, float* __restrict__ out) {
    if (threadIdx.x == 0) {
        const double Nd = (double)NROWS;
        double recons_loss = ws[0] / (double)IMG_ELEMS;
        double kld = -0.5 * ws[1] / Nd;
        double mmd = (ws[2] + ws[3] - 2.0 * ws[4]) / (Nd * Nd);
        double bias_corr = Nd * (Nd - 1.0);
        double loss = 5.0 * recons_loss
                    + 1.5 * (1.0 / Nd) * kld
                    + (98.5 / bias_corr) * mmd;
        out[0] = (float)loss;
        out[1] = (float)recons_loss;
        out[2] = (float)mmd;
        out[3] = (float)(-kld);
    }
}

extern "C" void kernel_launch(void* const* d_in, const int* in_sizes, int n_in,
                              void* d_out, int out_size, void* d_ws, size_t ws_size,
                              hipStream_t stream) {
    const float* recons  = (const float*)d_in[0];
    const float* x       = (const float*)d_in[1];
    const float* z       = (const float*)d_in[2];
    const float* mu      = (const float*)d_in[3];
    const float* log_var = (const float*)d_in[4];
    const float* prior_z = (const float*)d_in[5];
    double* ws = (double*)d_ws;
    char* wsb = (char*)d_ws;
    float* out = (float*)d_out;

    prep_kernel<<<2048, 256, 0, stream>>>(prior_z, z, wsb, ws);
    fused_kernel<<<TOTAL_BLOCKS, 256, 0, stream>>>(wsb, ws,
                                                   (const floatx4*)recons,
                                                   (const floatx4*)x,
                                                   (const floatx4*)mu,
                                                   (const floatx4*)log_var);
    finalize_kernel<<<1, 64, 0, stream>>>(ws, out);
}

// Round 6
// 431.263 us; speedup vs baseline: 1.0478x; 1.0478x over previous
//
#include <hip/hip_runtime.h>
#include <math.h>

#define NROWS 4096
#define DDIM  128
#define IMG_ELEMS 50331648LL   // 4096*3*64*64

typedef __attribute__((ext_vector_type(8))) short short8;   // 8 bf16 = 4 VGPRs
typedef __attribute__((ext_vector_type(4))) float floatx4;  // MFMA acc / float4 loads

// ws layout (bytes):
//   [0,64)        : 5 doubles  [0]=mse [1]=kld [2]=Spp [3]=Szz [4]=Spz
//   [64, +16K)    : nP (4096 f32 row norms of prior_z)
//   [.. , +16K)   : nZ
//   then 4 x 1MB  : Phi, Plo, Zhi, Zlo (bf16 as ushort, 4096x128,
//                   FRAGMENT-LINEAR layout: elem (r,c) at
//                   ((r>>4)*4 + (c>>5))*512 + (((c>>3)&3)*16 + (r&15))*8 + (c&7)
//                   so one MFMA fragment = contiguous 1KB in lane order)
#define WS_NP   64
#define WS_NZ   (WS_NP + 16384)
#define WS_PHI  (WS_NZ + 16384)
#define WS_PLO  (WS_PHI + 1048576)
#define WS_ZHI  (WS_PLO + 1048576)
#define WS_ZLO  (WS_ZHI + 1048576)

// Persistent grid: 768 blocks = 3 per CU (VGPR 140 -> 3 blocks/CU), all
// co-resident for the whole kernel. Roles by bid%3:
//   %3==2 : gram-first (256 blocks, 8-9 serial tiles), then 40 mse units
//   %3!=2 : streamer (512 blocks; first 64 do the kld prefix), 76 mse units
// mse unit = 256 consecutive float4s (4KB) of each array.
// 256*40 + 512*76 = 49152 units = 12,582,912 float4s per array.  Weighted so
// gram blocks' serial gram time + small share ~= streamers' big share.
#define TOTAL_BLOCKS 768
#define GRAM_TILES   2080
#define MSE_UNITS_G  40
#define MSE_UNITS_S  76
#define KLD_CHUNKS   64

__device__ __forceinline__ unsigned short f2bf(float f) {
    unsigned u = __float_as_uint(f);
    unsigned r = (u + 0x7FFFu + ((u >> 16) & 1u)) >> 16;   // RNE
    return (unsigned short)r;
}
__device__ __forceinline__ float bf2f(unsigned short h) {
    return __uint_as_float(((unsigned)h) << 16);
}

// 2048 blocks x 256 threads; each wave owns one of 8192 rows (P then Z).
// Splits fp32 -> bf16 hi+lo into FRAGMENT-LINEAR layout, computes exact fp32
// row norms. Block 0 also zeroes the accumulator doubles.
__global__ __launch_bounds__(256) void prep_kernel(const float* __restrict__ P,
                                                   const float* __restrict__ Z,
                                                   char* __restrict__ wsb,
                                                   double* __restrict__ ws) {
    if (blockIdx.x == 0 && threadIdx.x < 8) ws[threadIdx.x] = 0.0;
    const int w = threadIdx.x >> 6;
    const int b = blockIdx.x * 4 + w;    // 0..8191
    const int row = b & 4095;
    const float* src;
    unsigned short *hi, *lo;
    float* nrm;
    if (b < 4096) {
        src = P + (size_t)row * DDIM;
        hi = (unsigned short*)(wsb + WS_PHI);
        lo = (unsigned short*)(wsb + WS_PLO);
        nrm = (float*)(wsb + WS_NP);
    } else {
        src = Z + (size_t)row * DDIM;
        hi = (unsigned short*)(wsb + WS_ZHI);
        lo = (unsigned short*)(wsb + WS_ZLO);
        nrm = (float*)(wsb + WS_NZ);
    }
    const int l = threadIdx.x & 63;      // lane holds cols 2l, 2l+1
    float2 v = ((const float2*)src)[l];
    unsigned short hx = f2bf(v.x), hy = f2bf(v.y);
    unsigned short lx = f2bf(v.x - bf2f(hx)), ly = f2bf(v.y - bf2f(hy));
    // fragment-linear destination (e and e+1 are contiguous: e in {0,2,4,6})
    const int rb = row >> 4, fr = row & 15;
    const int kb = l >> 4, fq = (l >> 2) & 3, e = (l & 3) * 2;
    const int dst = (rb * 4 + kb) * 512 + (fq * 16 + fr) * 8 + e;   // elems
    *(ushort2*)(hi + dst) = make_ushort2(hx, hy);
    *(ushort2*)(lo + dst) = make_ushort2(lx, ly);
    float s = v.x * v.x + v.y * v.y;
    #pragma unroll
    for (int o = 32; o > 0; o >>= 1) s += __shfl_down(s, o);
    if (l == 0) nrm[row] = s;
}

__global__ __launch_bounds__(256) void fused_kernel(char* __restrict__ wsb,
                                                    double* __restrict__ ws,
                                                    const floatx4* __restrict__ rc,
                                                    const floatx4* __restrict__ xx,
                                                    const floatx4* __restrict__ mu,
                                                    const floatx4* __restrict__ lv) {
    const int bid = blockIdx.x;
    const int tid = threadIdx.x, lane = tid & 63, w = tid >> 6;
    const int role = bid % 3;

    double accM = 0.0, accK = 0.0;
    __shared__ double red[4];
    __shared__ double smM[4], smK[4];

    int u0, u1;   // mse unit range for this block

    if (role == 2) {
        // ---------------- GRAM phase: serial no-LDS fragment-linear tiles --
        const int gid = bid / 3;                       // 0..255
        const int ntile = (gid < 32) ? 9 : 8;          // 2080 = 256*8 + 32

        const unsigned short* Phi = (const unsigned short*)(wsb + WS_PHI);
        const unsigned short* Plo = (const unsigned short*)(wsb + WS_PLO);
        const unsigned short* Zhi = (const unsigned short*)(wsb + WS_ZHI);
        const unsigned short* Zlo = (const unsigned short*)(wsb + WS_ZLO);
        const float* nP = (const float*)(wsb + WS_NP);
        const float* nZ = (const float*)(wsb + WS_NZ);

        for (int rep = 0; rep < ntile; ++rep) {
            const int t = (rep < 8) ? (gid + 256 * rep) : (2048 + gid);
            // t in [0,2080): [0,528)=pp upper, [528,1056)=zz upper, rest pz
            int g, by, bx;
            float wgt = 1.f;
            if (t < 1056) {
                g = (t < 528) ? 0 : 1;
                const int u = (t < 528) ? t : t - 528;
                int r = (int)((65.0f - sqrtf(4225.0f - 8.0f * (float)u)) * 0.5f);
                while ((r + 1) * (64 - r) / 2 <= u) ++r;    // cnt(r+1) <= u
                while (r * (65 - r) / 2 > u) --r;           // cnt(r) > u
                const int c = r + (u - r * (65 - r) / 2);
                by = r; bx = c;
                if (r != c) wgt = 2.f;            // off-diagonal counts twice
            } else {
                g = 2;
                const int u = t - 1056;
                by = u >> 5; bx = u & 31;
            }

            const unsigned short *Ahi, *Alo, *Bhi, *Blo;
            const float *nI, *nJ;
            if (g == 0)      { Ahi = Phi; Alo = Plo; Bhi = Phi; Blo = Plo; nI = nP; nJ = nP; }
            else if (g == 1) { Ahi = Zhi; Alo = Zlo; Bhi = Zhi; Blo = Zlo; nI = nZ; nJ = nZ; }
            else             { Ahi = Phi; Alo = Plo; Bhi = Zhi; Blo = Zlo; nI = nP; nJ = nZ; }

            const int i0 = by * 128, j0 = bx * 128;
            const int qi = (w >> 1) * 64, qj = (w & 1) * 64;
            const int ra = (i0 + qi) >> 4;       // 16-row fragment block, A
            const int rbb = (j0 + qj) >> 4;      // B side

            floatx4 acc[4][4];
            const floatx4 zero4 = {0.f, 0.f, 0.f, 0.f};
            #pragma unroll
            for (int a = 0; a < 4; a++)
                #pragma unroll
                for (int b = 0; b < 4; b++) acc[a][b] = zero4;

            #pragma unroll
            for (int pass = 0; pass < 3; pass++) {
                const short8* As = (const short8*)((pass == 2) ? Alo : Ahi);  // hi,hi,lo
                const short8* Bs = (const short8*)((pass == 1) ? Blo : Bhi);  // hi,lo,hi
                #pragma unroll
                for (int kb = 0; kb < 4; kb++) {
                    short8 af[4], bf[4];
                    #pragma unroll
                    for (int a = 0; a < 4; a++)
                        af[a] = As[((ra + a) * 4 + kb) * 64 + lane];  // 1KB/wave
                    #pragma unroll
                    for (int b = 0; b < 4; b++)
                        bf[b] = Bs[((rbb + b) * 4 + kb) * 64 + lane];
                    #pragma unroll
                    for (int a = 0; a < 4; a++)
                        #pragma unroll
                        for (int b = 0; b < 4; b++)
                            acc[a][b] = __builtin_amdgcn_mfma_f32_16x16x32_bf16(
                                af[a], bf[b], acc[a][b], 0, 0, 0);
                }
            }

            // epilogue: k_ij = exp(cc*(2*dot - ni - nj)), cc = 1/(D*2*D*z_var)
            const float cc = 1.0f / 65536.0f;
            const int fr = lane & 15, fq = lane >> 4;
            float nj_[4];
            #pragma unroll
            for (int b = 0; b < 4; b++) nj_[b] = nJ[j0 + qj + b * 16 + fr];
            float sum = 0.f;
            #pragma unroll
            for (int a = 0; a < 4; a++) {
                #pragma unroll
                for (int r = 0; r < 4; r++) {
                    const float ni = nI[i0 + qi + a * 16 + fq * 4 + r];
                    #pragma unroll
                    for (int b = 0; b < 4; b++)
                        sum += expf(cc * (2.f * acc[a][b][r] - ni - nj_[b]));
                }
            }
            sum *= wgt;

            double v = (double)sum;
            #pragma unroll
            for (int o = 32; o > 0; o >>= 1) v += __shfl_down(v, o);
            if (lane == 0) red[w] = v;
            __syncthreads();
            if (tid == 0) atomicAdd(&ws[2 + g], red[0] + red[1] + red[2] + red[3]);
            __syncthreads();   // red[] safe for next tile
        }
        const int gid2 = bid / 3;
        u0 = gid2 * MSE_UNITS_G;
        u1 = u0 + MSE_UNITS_G;
    } else {
        const int sid = (bid / 3) * 2 + role;          // 0..511
        if (sid < KLD_CHUNKS) {
            // ------------- KLD prefix: contiguous 32KB chunk per array -----
            const int i = sid * 2048 + tid;
            float sm = 0.f;
            #pragma unroll
            for (int q = 0; q < 8; ++q) {
                floatx4 m = mu[i + q * 256], l = lv[i + q * 256];
                sm += (1.f + l[0] - m[0] * m[0] - __expf(l[0]) )
                    + (1.f + l[1] - m[1] * m[1] - __expf(l[1]) )
                    + (1.f + l[2] - m[2] * m[2] - __expf(l[2]) )
                    + (1.f + l[3] - m[3] * m[3] - __expf(l[3]) );
            }
            accK = (double)sm;
        }
        u0 = 256 * MSE_UNITS_G + sid * MSE_UNITS_S;
        u1 = u0 + MSE_UNITS_S;
    }

    // ---------------- MSE phase: contiguous NT stream, rc/xx interleaved ---
    {
        floatx4 s0 = {0.f,0.f,0.f,0.f}, s1 = s0, s2 = s0, s3 = s0;
        #pragma unroll 1
        for (int u = u0; u < u1; u += 4) {
            const long long i = (long long)u * 256 + tid;
            floatx4 a0 = __builtin_nontemporal_load(rc + i);
            floatx4 b0 = __builtin_nontemporal_load(xx + i);
            floatx4 a1 = __builtin_nontemporal_load(rc + i + 256);
            floatx4 b1 = __builtin_nontemporal_load(xx + i + 256);
            floatx4 a2 = __builtin_nontemporal_load(rc + i + 512);
            floatx4 b2 = __builtin_nontemporal_load(xx + i + 512);
            floatx4 a3 = __builtin_nontemporal_load(rc + i + 768);
            floatx4 b3 = __builtin_nontemporal_load(xx + i + 768);
            floatx4 d0 = a0 - b0, d1 = a1 - b1, d2 = a2 - b2, d3 = a3 - b3;
            s0 += d0 * d0; s1 += d1 * d1; s2 += d2 * d2; s3 += d3 * d3;
        }
        floatx4 st = (s0 + s1) + (s2 + s3);
        accM = ((double)st[0] + (double)st[1]) + ((double)st[2] + (double)st[3]);
    }

    // ---------------- one combined block reduction -> 2 atomics ------------
    #pragma unroll
    for (int o = 32; o > 0; o >>= 1) {
        accM += __shfl_down(accM, o);
        accK += __shfl_down(accK, o);
    }
    if (lane == 0) { smM[w] = accM; smK[w] = accK; }
    __syncthreads();
    if (tid == 0) {
        atomicAdd(&ws[0], smM[0] + smM[1] + smM[2] + smM[3]);
        atomicAdd(&ws[1], smK[0] + smK[1] + smK[2] + smK[3]);
    }
}

__global__ void finalize_kernel(const double* __restrict__ ws, float* __restrict__ out) {
    if (threadIdx.x == 0) {
        const double Nd = (double)NROWS;
        double recons_loss = ws[0] / (double)IMG_ELEMS;
        double kld = -0.5 * ws[1] / Nd;
        double mmd = (ws[2] + ws[3] - 2.0 * ws[4]) / (Nd * Nd);
        double bias_corr = Nd * (Nd - 1.0);
        double loss = 5.0 * recons_loss
                    + 1.5 * (1.0 / Nd) * kld
                    + (98.5 / bias_corr) * mmd;
        out[0] = (float)loss;
        out[1] = (float)recons_loss;
        out[2] = (float)mmd;
        out[3] = (float)(-kld);
    }
}

extern "C" void kernel_launch(void* const* d_in, const int* in_sizes, int n_in,
                              void* d_out, int out_size, void* d_ws, size_t ws_size,
                              hipStream_t stream) {
    const float* recons  = (const float*)d_in[0];
    const float* x       = (const float*)d_in[1];
    const float* z       = (const float*)d_in[2];
    const float* mu      = (const float*)d_in[3];
    const float* log_var = (const float*)d_in[4];
    const float* prior_z = (const float*)d_in[5];
    double* ws = (double*)d_ws;
    char* wsb = (char*)d_ws;
    float* out = (float*)d_out;

    prep_kernel<<<2048, 256, 0, stream>>>(prior_z, z, wsb, ws);
    fused_kernel<<<TOTAL_BLOCKS, 256, 0, stream>>>(wsb, ws,
                                                   (const floatx4*)recons,
                                                   (const floatx4*)x,
                                                   (const floatx4*)mu,
                                                   (const floatx4*)log_var);
    finalize_kernel<<<1, 64, 0, stream>>>(ws, out);
}

// Round 7
// 408.188 us; speedup vs baseline: 1.1070x; 1.0565x over previous
//
#include <hip/hip_runtime.h>
#include <math.h>

#define NROWS 4096
#define DDIM  128
#define IMG_ELEMS 50331648LL   // 4096*3*64*64

typedef __attribute__((ext_vector_type(8))) short short8;   // 8 bf16 = 4 VGPRs
typedef __attribute__((ext_vector_type(4))) float floatx4;  // MFMA acc / float4 loads

// ws layout (bytes):
//   [0,64)        : 5 doubles  [0]=mse [1]=kld [2]=Spp [3]=Szz [4]=Spz
//   [64, +16K)    : nP (4096 f32 row norms of prior_z)
//   [.. , +16K)   : nZ
//   then 4 x 1MB  : Phi, Plo, Zhi, Zlo (bf16 as ushort, 4096x128 ROW-MAJOR)
#define WS_NP   64
#define WS_NZ   (WS_NP + 16384)
#define WS_PHI  (WS_NZ + 16384)
#define WS_PLO  (WS_PHI + 1048576)
#define WS_ZHI  (WS_PLO + 1048576)
#define WS_ZLO  (WS_ZHI + 1048576)

// Champion structure (r1, 410.15 us): 32 groups of 105 blocks.
// Per group: 65 gram + 32 mse + 8 kld  => 2080 gram / 1024 mse / 256 kld.
// gram 2080 = 528 pp-upper + 528 zz-upper + 1024 pz-full (triangle trick),
// LDS-staged (async global_load_lds), which shares each tile read across the
// block (no-LDS variant doubles L2 traffic and measured ~13us slower).
#define GROUP        105
#define NGROUPS      32
#define TOTAL_BLOCKS (GROUP * NGROUPS)
#define MSE_BLOCKS   1024
#define KLD_BLOCKS   256

__device__ __forceinline__ unsigned short f2bf(float f) {
    unsigned u = __float_as_uint(f);
    unsigned r = (u + 0x7FFFu + ((u >> 16) & 1u)) >> 16;   // RNE
    return (unsigned short)r;
}
__device__ __forceinline__ float bf2f(unsigned short h) {
    return __uint_as_float(((unsigned)h) << 16);
}

__device__ __forceinline__ void async_ld16(const void* g, void* l) {
    __builtin_amdgcn_global_load_lds(
        (const __attribute__((address_space(1))) unsigned int*)g,
        (__attribute__((address_space(3))) unsigned int*)l, 16, 0, 0);
}

__device__ __forceinline__ void block_reduce_atomic(double v, double* dst) {
    #pragma unroll
    for (int o = 32; o > 0; o >>= 1) v += __shfl_down(v, o);
    __shared__ double sm[4];
    int lane = threadIdx.x & 63, wv = threadIdx.x >> 6;
    if (lane == 0) sm[wv] = v;
    __syncthreads();
    if (threadIdx.x == 0) atomicAdd(dst, sm[0] + sm[1] + sm[2] + sm[3]);
}

// 2048 blocks x 256 threads; each wave owns one of 8192 rows (P then Z).
// Splits fp32 -> bf16 hi+lo (row-major), computes exact fp32 row norms.
// Block 0 also zeroes the accumulator doubles (consumed only by NEXT launch).
__global__ __launch_bounds__(256) void prep_kernel(const float* __restrict__ P,
                                                   const float* __restrict__ Z,
                                                   char* __restrict__ wsb,
                                                   double* __restrict__ ws) {
    if (blockIdx.x == 0 && threadIdx.x < 8) ws[threadIdx.x] = 0.0;
    const int w = threadIdx.x >> 6;
    const int b = blockIdx.x * 4 + w;    // 0..8191
    const int row = b & 4095;
    const float* src;
    unsigned short *hi, *lo;
    float* nrm;
    if (b < 4096) {
        src = P + (size_t)row * DDIM;
        hi = (unsigned short*)(wsb + WS_PHI) + (size_t)row * DDIM;
        lo = (unsigned short*)(wsb + WS_PLO) + (size_t)row * DDIM;
        nrm = (float*)(wsb + WS_NP);
    } else {
        src = Z + (size_t)row * DDIM;
        hi = (unsigned short*)(wsb + WS_ZHI) + (size_t)row * DDIM;
        lo = (unsigned short*)(wsb + WS_ZLO) + (size_t)row * DDIM;
        nrm = (float*)(wsb + WS_NZ);
    }
    const int l = threadIdx.x & 63;
    float2 v = ((const float2*)src)[l];
    unsigned short hx = f2bf(v.x), hy = f2bf(v.y);
    unsigned short lx = f2bf(v.x - bf2f(hx)), ly = f2bf(v.y - bf2f(hy));
    ((ushort2*)hi)[l] = make_ushort2(hx, hy);
    ((ushort2*)lo)[l] = make_ushort2(lx, ly);
    float s = v.x * v.x + v.y * v.y;
    #pragma unroll
    for (int o = 32; o > 0; o >>= 1) s += __shfl_down(s, o);
    if (l == 0) nrm[row] = s;
}

// One kernel, three block roles, interleaved so memory-bound (mse/kld) waves
// co-schedule with MFMA-bound (gram) waves on every CU.
__global__ __launch_bounds__(256) void fused_kernel(char* __restrict__ wsb,
                                                    double* __restrict__ ws,
                                                    const floatx4* __restrict__ rc,
                                                    const floatx4* __restrict__ xx,
                                                    const floatx4* __restrict__ mu,
                                                    const floatx4* __restrict__ lv) {
    __shared__ __align__(16) unsigned short sA[128 * 32];
    __shared__ __align__(16) unsigned short sB[128 * 32];

    const int bid = blockIdx.x;
    const int grp = bid / GROUP, slot = bid % GROUP;
    const int tid = threadIdx.x;

    if (slot >= 65) {
        if (slot < 97) {
            // ---------------- MSE role ----------------
            const int midx = grp * 32 + (slot - 65);          // 0..1023
            const long long S = (long long)MSE_BLOCKS * 256;  // 262144 float4s
            const long long base = (long long)midx * 256 + tid;
            floatx4 s0 = {0.f,0.f,0.f,0.f}, s1 = s0, s2 = s0, s3 = s0;
            #pragma unroll 1
            for (int it = 0; it < 12; ++it) {
                long long i = base + (long long)(it * 4) * S;
                floatx4 a0 = __builtin_nontemporal_load(rc + i);
                floatx4 b0 = __builtin_nontemporal_load(xx + i);
                floatx4 a1 = __builtin_nontemporal_load(rc + i + S);
                floatx4 b1 = __builtin_nontemporal_load(xx + i + S);
                floatx4 a2 = __builtin_nontemporal_load(rc + i + 2 * S);
                floatx4 b2 = __builtin_nontemporal_load(xx + i + 2 * S);
                floatx4 a3 = __builtin_nontemporal_load(rc + i + 3 * S);
                floatx4 b3 = __builtin_nontemporal_load(xx + i + 3 * S);
                floatx4 d0 = a0 - b0, d1 = a1 - b1, d2 = a2 - b2, d3 = a3 - b3;
                s0 += d0 * d0; s1 += d1 * d1; s2 += d2 * d2; s3 += d3 * d3;
            }
            floatx4 st = (s0 + s1) + (s2 + s3);
            double v = ((double)st[0] + (double)st[1]) + ((double)st[2] + (double)st[3]);
            block_reduce_atomic(v, &ws[0]);
            return;
        } else {
            // ---------------- KLD role ----------------
            const int kidx = grp * 8 + (slot - 97);           // 0..255
            const int i = kidx * 256 + tid;
            float s = 0.f;
            #pragma unroll
            for (int h = 0; h < 2; ++h) {
                floatx4 m = mu[i + h * 65536], l = lv[i + h * 65536];
                s += (1.f + l[0] - m[0] * m[0] - __expf(l[0]) )
                   + (1.f + l[1] - m[1] * m[1] - __expf(l[1]) )
                   + (1.f + l[2] - m[2] * m[2] - __expf(l[2]) )
                   + (1.f + l[3] - m[3] * m[3] - __expf(l[3]) );
            }
            block_reduce_atomic((double)s, &ws[1]);
            return;
        }
    }

    // ---------------- GRAM role ----------------
    // t in [0,2080): [0,528)=pp upper, [528,1056)=zz upper, [1056,2080)=pz full
    const int t = grp * 65 + slot;
    int g, by, bx;
    float wgt = 1.f;
    if (t < 1056) {
        g = (t < 528) ? 0 : 1;
        const int u = (t < 528) ? t : t - 528;
        int r = (int)((65.0f - sqrtf(4225.0f - 8.0f * (float)u)) * 0.5f);
        while ((r + 1) * (64 - r) / 2 <= u) ++r;    // cnt(r+1) <= u
        while (r * (65 - r) / 2 > u) --r;           // cnt(r) > u
        const int c = r + (u - r * (65 - r) / 2);
        by = r; bx = c;
        if (r != c) wgt = 2.f;                      // off-diagonal tile counts twice
    } else {
        g = 2;
        const int u = t - 1056;
        by = u >> 5; bx = u & 31;
    }

    const unsigned short *Ahi, *Alo, *Bhi, *Blo;
    const float *nI, *nJ;
    const unsigned short* Phi = (const unsigned short*)(wsb + WS_PHI);
    const unsigned short* Plo = (const unsigned short*)(wsb + WS_PLO);
    const unsigned short* Zhi = (const unsigned short*)(wsb + WS_ZHI);
    const unsigned short* Zlo = (const unsigned short*)(wsb + WS_ZLO);
    const float* nP = (const float*)(wsb + WS_NP);
    const float* nZ = (const float*)(wsb + WS_NZ);
    if (g == 0)      { Ahi = Phi; Alo = Plo; Bhi = Phi; Blo = Plo; nI = nP; nJ = nP; }
    else if (g == 1) { Ahi = Zhi; Alo = Zlo; Bhi = Zhi; Blo = Zlo; nI = nZ; nJ = nZ; }
    else             { Ahi = Phi; Alo = Plo; Bhi = Zhi; Blo = Zlo; nI = nP; nJ = nZ; }

    const int i0 = by * 128, j0 = bx * 128;
    const int lane = tid & 63, w = tid >> 6;
    const int qi = (w >> 1) * 64, qj = (w & 1) * 64;

    floatx4 acc[4][4];
    const floatx4 zero4 = {0.f, 0.f, 0.f, 0.f};
    #pragma unroll
    for (int a = 0; a < 4; a++)
        #pragma unroll
        for (int b = 0; b < 4; b++) acc[a][b] = zero4;

    const int fr = lane & 15, fq = lane >> 4;

    #pragma unroll
    for (int pass = 0; pass < 3; pass++) {
        const unsigned short* As = (pass == 2) ? Alo : Ahi;  // hi,hi,lo
        const unsigned short* Bs = (pass == 1) ? Blo : Bhi;  // hi,lo,hi
        for (int kc = 0; kc < DDIM; kc += 32) {
            __syncthreads();   // readers of previous chunk done
            #pragma unroll
            for (int tt = 0; tt < 2; tt++) {
                // wave-inst covers 1024B contiguous LDS: base=(tt*4+w)*1024 + lane*16
                const int r  = ((tt * 4 + w) << 4) + (lane >> 2);
                const int ko = (lane & 3) * 8;                       // bf16 elems
                async_ld16(As + (size_t)(i0 + r) * DDIM + kc + ko,
                           (char*)sA + r * 64 + ko * 2);
                async_ld16(Bs + (size_t)(j0 + r) * DDIM + kc + ko,
                           (char*)sB + r * 64 + ko * 2);
            }
            __syncthreads();   // vmcnt(0) drain before barrier completes staging

            short8 af[4], bf[4];
            #pragma unroll
            for (int a = 0; a < 4; a++)
                af[a] = *(const short8*)((const char*)sA + (qi + a * 16 + fr) * 64 + fq * 16);
            #pragma unroll
            for (int b = 0; b < 4; b++)
                bf[b] = *(const short8*)((const char*)sB + (qj + b * 16 + fr) * 64 + fq * 16);
            #pragma unroll
            for (int a = 0; a < 4; a++)
                #pragma unroll
                for (int b = 0; b < 4; b++)
                    acc[a][b] = __builtin_amdgcn_mfma_f32_16x16x32_bf16(
                        af[a], bf[b], acc[a][b], 0, 0, 0);
        }
    }

    // epilogue: k_ij = exp(cc*(2*dot - ni - nj)), cc = 1/(D * 2*D*z_var)
    const float cc = 1.0f / 65536.0f;
    float nj_[4];
    #pragma unroll
    for (int b = 0; b < 4; b++) nj_[b] = nJ[j0 + qj + b * 16 + fr];
    float sum = 0.f;
    #pragma unroll
    for (int a = 0; a < 4; a++) {
        #pragma unroll
        for (int r = 0; r < 4; r++) {
            const float ni = nI[i0 + qi + a * 16 + fq * 4 + r];
            #pragma unroll
            for (int b = 0; b < 4; b++)
                sum += expf(cc * (2.f * acc[a][b][r] - ni - nj_[b]));
        }
    }
    sum *= wgt;

    double v = (double)sum;
    #pragma unroll
    for (int o = 32; o > 0; o >>= 1) v += __shfl_down(v, o);
    __shared__ double red[4];
    if (lane == 0) red[w] = v;
    __syncthreads();
    if (tid == 0) atomicAdd(&ws[2 + g], red[0] + red[1] + red[2] + red[3]);
}

__global__ void finalize_kernel(const double* __restrict__ ws, float* __restrict__ out) {
    if (threadIdx.x == 0) {
        const double Nd = (double)NROWS;
        double recons_loss = ws[0] / (double)IMG_ELEMS;
        double kld = -0.5 * ws[1] / Nd;
        double mmd = (ws[2] + ws[3] - 2.0 * ws[4]) / (Nd * Nd);
        double bias_corr = Nd * (Nd - 1.0);
        double loss = 5.0 * recons_loss
                    + 1.5 * (1.0 / Nd) * kld
                    + (98.5 / bias_corr) * mmd;
        out[0] = (float)loss;
        out[1] = (float)recons_loss;
        out[2] = (float)mmd;
        out[3] = (float)(-kld);
    }
}

extern "C" void kernel_launch(void* const* d_in, const int* in_sizes, int n_in,
                              void* d_out, int out_size, void* d_ws, size_t ws_size,
                              hipStream_t stream) {
    const float* recons  = (const float*)d_in[0];
    const float* x       = (const float*)d_in[1];
    const float* z       = (const float*)d_in[2];
    const float* mu      = (const float*)d_in[3];
    const float* log_var = (const float*)d_in[4];
    const float* prior_z = (const float*)d_in[5];
    double* ws = (double*)d_ws;
    char* wsb = (char*)d_ws;
    float* out = (float*)d_out;

    prep_kernel<<<2048, 256, 0, stream>>>(prior_z, z, wsb, ws);
    fused_kernel<<<TOTAL_BLOCKS, 256, 0, stream>>>(wsb, ws,
                                                   (const floatx4*)recons,
                                                   (const floatx4*)x,
                                                   (const floatx4*)mu,
                                                   (const floatx4*)log_var);
    finalize_kernel<<<1, 64, 0, stream>>>(ws, out);
}